// Round 15
// baseline (292.956 us; speedup 1.0000x reference)
//
#include <hip/hip_runtime.h>
#include <hip/hip_fp16.h>
#include <math.h>

constexpr int LI = 8192;   // I (intermediate)
constexpr int LD = 2048;   // D (hidden)
constexpr int LN = 2048;   // N (tokens)
constexpr int LK = 32;     // top_k
constexpr int CAP = 192;   // candidate band cap per row
constexpr int DEPTH = 96;  // per-neuron inverted-list bucket depth

typedef short short8 __attribute__((ext_vector_type(8)));
typedef unsigned short ushort8 __attribute__((ext_vector_type(8)));
typedef _Float16 half8 __attribute__((ext_vector_type(8)));
typedef float f32x4 __attribute__((ext_vector_type(4)));
typedef const __attribute__((address_space(1))) void* gas1_t;
typedef __attribute__((address_space(3))) void* las3_t;

__device__ __forceinline__ void gload16(const void* g, void* l) {
    __builtin_amdgcn_global_load_lds((gas1_t)g, (las3_t)l, 16, 0, 0);
}
__device__ __forceinline__ unsigned short f2bf_rne(float f) {
    unsigned u = __float_as_uint(f);
    return (unsigned short)((u + 0x7fffu + ((u >> 16) & 1u)) >> 16);
}
__device__ __forceinline__ unsigned short f2h_rne(float f) {   // fp16 RNE bits
    return __half_as_ushort(__float2half(f));
}
__device__ __forceinline__ float h2f(unsigned short u) {
    return __half2float(__ushort_as_half(u));
}

// ---- fused fp32->fp16 convert: blocks [0,512) = x, [512,2560) = gate[l],
//      block 2560 zeroes ghist. 8 floats/thread, 16B ushort8 stores.
__global__ __launch_bounds__(256) void k_cvt2(
    const float* __restrict__ x, const float* __restrict__ gate,
    const int* __restrict__ layer_idx,
    unsigned short* __restrict__ xh, unsigned short* __restrict__ wh,
    int* __restrict__ ghist)
{
    if (blockIdx.x >= 2560) {          // ghist zero (replaces hipMemsetAsync)
        int t = threadIdx.x;
        #pragma unroll
        for (int b = 0; b < 32; ++b) ghist[t * 32 + b] = 0;
        return;
    }
    const float* src; unsigned short* dst; int n8, bid, nb;
    if (blockIdx.x < 512) {
        src = x; dst = xh; n8 = (LN * LD) / 8; bid = blockIdx.x; nb = 512;
    } else {
        src = gate + (size_t)layer_idx[0] * LI * LD; dst = wh;
        n8 = (LI * LD) / 8; bid = blockIdx.x - 512; nb = 2048;
    }
    int i = bid * 256 + threadIdx.x;
    int stride = nb * 256;
    for (; i < n8; i += stride) {
        f32x4 v0 = *(const f32x4*)(src + 8 * (size_t)i);
        f32x4 v1 = *(const f32x4*)(src + 8 * (size_t)i + 4);
        ushort8 h;
        h[0] = f2h_rne(v0[0]); h[1] = f2h_rne(v0[1]);
        h[2] = f2h_rne(v0[2]); h[3] = f2h_rne(v0[3]);
        h[4] = f2h_rne(v1[0]); h[5] = f2h_rne(v1[1]);
        h[6] = f2h_rne(v1[2]); h[7] = f2h_rne(v1[3]);
        ((ushort8*)dst)[i] = h;
    }
}

// ---- zk = fp16(|silu(x @ gw^T)|) via fp16 MFMA, 128x128 tile, BK=64.
// Standalone again (transpose un-fused). Structure verified rounds 4-14.
__global__ __launch_bounds__(256) void k_gemm(
    const unsigned short* __restrict__ xh, const unsigned short* __restrict__ wh,
    unsigned short* __restrict__ zk)
{
    __shared__ short lds[16384];   // Ah|Bh, each [128][64] fp16 = 16KB
    short* Ah = lds;
    short* Bh = lds + 8192;

    const int tid = threadIdx.x;
    const int w = tid >> 6, lane = tid & 63;
    const int flat = blockIdx.x;                     // 0..1023
    const int swz  = (flat & 7) * 128 + (flat >> 3); // bijective XCD swizzle
    const int bn = (swz >> 6) * 128;   // token rows
    const int bi = (swz & 63) * 128;   // neuron rows

    const int srow   = w * 32 + (lane >> 3);
    const int schunk = (lane & 7) ^ ((lane >> 3) & 7);
    const unsigned short* xbh = xh + (size_t)(bn + srow) * LD + schunk * 8;
    const unsigned short* wbh = wh + (size_t)(bi + srow) * LD + schunk * 8;

    f32x4 acc[4][4];
    #pragma unroll
    for (int m = 0; m < 4; ++m)
        #pragma unroll
        for (int n = 0; n < 4; ++n) acc[m][n] = (f32x4){0.f, 0.f, 0.f, 0.f};

    const int wm = (w >> 1) * 64, wn = (w & 1) * 64;

    #define STAGE(k0)                                                          \
        {                                                                      \
            _Pragma("unroll")                                                  \
            for (int t = 0; t < 4; ++t) {                                      \
                int ldo = (w * 32 + t * 8) * 64;                               \
                size_t go = (size_t)t * 8 * LD + (k0);                         \
                gload16(xbh + go, Ah + ldo);                                   \
                gload16(wbh + go, Bh + ldo);                                   \
            }                                                                  \
        }

    STAGE(0);
    __syncthreads();
    for (int k0 = 0;;) {
        #pragma unroll
        for (int ks = 0; ks < 2; ++ks) {
            half8 a_h[4], b_h[4];
            #pragma unroll
            for (int m = 0; m < 4; ++m) {
                int lr = wm + m * 16 + (lane & 15);
                int lc = ks * 4 + (lane >> 4);
                a_h[m] = *(const half8*)(Ah + lr * 64 + ((lc ^ (lr & 7)) << 3));
            }
            #pragma unroll
            for (int n = 0; n < 4; ++n) {
                int lr = wn + n * 16 + (lane & 15);
                int lc = ks * 4 + (lane >> 4);
                b_h[n] = *(const half8*)(Bh + lr * 64 + ((lc ^ (lr & 7)) << 3));
            }
            #pragma unroll
            for (int m = 0; m < 4; ++m)
                #pragma unroll
                for (int n = 0; n < 4; ++n)
                    acc[m][n] = __builtin_amdgcn_mfma_f32_16x16x32_f16(a_h[m], b_h[n], acc[m][n], 0, 0, 0);
        }
        k0 += 64;
        if (k0 >= LD) break;
        __syncthreads();
        STAGE(k0);
        __syncthreads();
    }

    // epilogue: key = fp16(|silu(z)|)
    #pragma unroll
    for (int m = 0; m < 4; ++m) {
        int rb = bn + wm + m * 16 + (lane >> 4) * 4;
        #pragma unroll
        for (int n = 0; n < 4; ++n) {
            int cb = bi + wn + n * 16 + (lane & 15);
            #pragma unroll
            for (int r = 0; r < 4; ++r) {
                float zv = acc[m][n][r];
                float g = zv / (1.f + expf(-zv));
                zk[(size_t)(rb + r) * LI + cb] = f2h_rne(fabsf(g));
            }
        }
    }
    #undef STAGE
}

// ---- band selection on fp16 keys: 2048 bins of 4-ulp width over [0.25, 64),
// threshold bin covering rank-32, band = keys >= binfloor - 0.012.
__global__ __launch_bounds__(256) void k_select(
    const unsigned short* __restrict__ zk, int* __restrict__ band,
    int* __restrict__ bandcnt, int* __restrict__ ghist, int* __restrict__ inv)
{
    __shared__ int hist[2048];   // 8 KB
    __shared__ int sums[256];
    __shared__ int base_s;
    __shared__ int thrbin_s;

    const int row = blockIdx.x;
    const int tid = threadIdx.x;
    const int lane = tid & 63;
    const unsigned short* __restrict__ z = zk + (size_t)row * LI;

    if (tid == 0) { thrbin_s = 0; base_s = 0; }
    for (int i = tid; i < 2048; i += 256) hist[i] = 0;
    __syncthreads();

    ushort8 kv[4];
    #pragma unroll
    for (int c = 0; c < 4; ++c) {
        kv[c] = *(const ushort8*)(z + c * 2048 + tid * 8);
        #pragma unroll
        for (int j = 0; j < 8; ++j) {
            int b = (int)(kv[c][j] >> 2) - 3328;   // fp16 0.25 = 0x3400
            if (b > 0) {
                b = b > 2047 ? 2047 : b;
                atomicAdd(&hist[b], 1);
            }
        }
    }
    __syncthreads();

    int own = 0;
    #pragma unroll
    for (int b = 0; b < 8; ++b) own += hist[tid * 8 + b];
    sums[tid] = own;
    __syncthreads();
    for (int st = 1; st < 256; st <<= 1) {   // suffix inclusive scan
        int v = (tid + st < 256) ? sums[tid + st] : 0;
        __syncthreads();
        sums[tid] += v;
        __syncthreads();
    }
    int after = (tid < 255) ? sums[tid + 1] : 0;
    if (after < LK && after + own >= LK) {   // unique crossing thread
        int cum = after;
        for (int b = 7; b >= 0; --b) {
            cum += hist[tid * 8 + b];
            if (cum >= LK) { thrbin_s = tid * 8 + b; break; }
        }
    }
    __syncthreads();
    const float bandlo =
        h2f((unsigned short)((thrbin_s + 3328) << 2)) - 0.012f;

    #pragma unroll
    for (int c = 0; c < 4; ++c) {
        unsigned flags = 0;
        #pragma unroll
        for (int j = 0; j < 8; ++j) {
            if (h2f(kv[c][j]) >= bandlo) flags |= (1u << j);
        }
        int cnt = __popc(flags);
        int pre = cnt;                        // wave inclusive scan
        #pragma unroll
        for (int o = 1; o < 64; o <<= 1) {
            int v = __shfl_up(pre, o);
            if (lane >= o) pre += v;
        }
        int wtotal = __shfl(pre, 63);
        int excl = pre - cnt;
        int wbase = 0;
        if (lane == 63 && wtotal) wbase = atomicAdd(&base_s, wtotal);
        wbase = __shfl(wbase, 63);
        int pos = wbase + excl;
        while (flags) {
            int j = __ffs(flags) - 1;
            flags &= flags - 1;
            if (pos < CAP) {
                int gi = c * 2048 + tid * 8 + j;
                band[row * CAP + pos] = gi;
                int p = atomicAdd(&ghist[gi], 1);
                if (p < DEPTH) inv[gi * DEPTH + p] = (row << 8) | pos;
            }
            ++pos;
        }
    }
    __syncthreads();
    if (tid == 0) bandcnt[row] = base_s < CAP ? base_s : CAP;
}

// ---- FUSED: blocks [0,LI) = neuron-major exact rescore (pure gather,
// latency-bound); blocks [LI, LI+4096) = transpose down -> dT bf16 (pure BW).
// Transpose hides under pair's idle bandwidth (round-10/12-verified pairing).
__global__ __launch_bounds__(256) void k_pairT(
    const float* __restrict__ x, const float* __restrict__ gate,
    const float* __restrict__ up, const float* __restrict__ down,
    const int* __restrict__ layer_idx,
    const int* __restrict__ ghist, const int* __restrict__ inv,
    float* __restrict__ gdot, float* __restrict__ udot,
    unsigned short* __restrict__ dTb)
{
    __shared__ float smem[4160];   // pair: gs|us (16 KB); transpose: 64x65 tile
    const int tid = threadIdx.x;

    if (blockIdx.x >= LI) {
        // ---------------- transpose body: 64x64 tiles (verified r8-14) ------
        float (*t)[65] = (float(*)[65])smem;
        const float* __restrict__ dw = down + (size_t)layer_idx[0] * LD * LI;
        const int bid2 = blockIdx.x - LI;
        const int bi = (bid2 & 127) * 64;   // I
        const int bd = (bid2 >> 7) * 64;    // D
        const int tx = tid & 63, ty = tid >> 6;   // ty in [0,4)
        #pragma unroll
        for (int it = 0; it < 16; ++it) {
            int r = ty + it * 4;
            t[r][tx] = dw[(size_t)(bd + r) * LI + bi + tx];
        }
        __syncthreads();
        #pragma unroll
        for (int it = 0; it < 16; ++it) {
            int rr = ty + it * 4;
            dTb[(size_t)(bi + rr) * LD + bd + tx] = f2bf_rne(t[tx][rr]);
        }
        return;
    }

    // ---------------- pair body (round-10/13 verified) ----------------
    float* gs = smem;
    float* us = smem + LD;
    const int j = blockIdx.x;
    const int lane = tid & 63, w = tid >> 6;
    int nj = ghist[j];
    if (nj == 0) return;
    if (nj > DEPTH) nj = DEPTH;
    const float* __restrict__ gr = gate + (size_t)layer_idx[0] * LI * LD + (size_t)j * LD;
    const float* __restrict__ ur = up   + (size_t)layer_idx[0] * LI * LD + (size_t)j * LD;
    for (int i = tid * 4; i < LD; i += 1024) {
        *(f32x4*)&gs[i] = *(const f32x4*)(gr + i);
        *(f32x4*)&us[i] = *(const f32x4*)(ur + i);
    }
    __syncthreads();
    const int base = j * DEPTH;
    for (int e = w; e < nj; e += 4) {
        int packed = inv[base + e];
        int row = packed >> 8, slot = packed & 255;
        const float* __restrict__ xr = x + (size_t)row * LD;
        float gd0 = 0.f, gd1 = 0.f, ud0 = 0.f, ud1 = 0.f;
        #pragma unroll
        for (int it = 0; it < 8; it += 2) {
            int i0 = lane * 4 + it * 256;
            int i1 = i0 + 256;
            f32x4 xa = *(const f32x4*)(xr + i0);
            f32x4 xb = *(const f32x4*)(xr + i1);
            gd0 = fmaf(xa[0], gs[i0+0], gd0); gd0 = fmaf(xa[1], gs[i0+1], gd0);
            gd0 = fmaf(xa[2], gs[i0+2], gd0); gd0 = fmaf(xa[3], gs[i0+3], gd0);
            ud0 = fmaf(xa[0], us[i0+0], ud0); ud0 = fmaf(xa[1], us[i0+1], ud0);
            ud0 = fmaf(xa[2], us[i0+2], ud0); ud0 = fmaf(xa[3], us[i0+3], ud0);
            gd1 = fmaf(xb[0], gs[i1+0], gd1); gd1 = fmaf(xb[1], gs[i1+1], gd1);
            gd1 = fmaf(xb[2], gs[i1+2], gd1); gd1 = fmaf(xb[3], gs[i1+3], gd1);
            ud1 = fmaf(xb[0], us[i1+0], ud1); ud1 = fmaf(xb[1], us[i1+1], ud1);
            ud1 = fmaf(xb[2], us[i1+2], ud1); ud1 = fmaf(xb[3], us[i1+3], ud1);
        }
        float gd = gd0 + gd1, ud = ud0 + ud1;
        #pragma unroll
        for (int o = 32; o; o >>= 1) {
            gd += __shfl_down(gd, o);
            ud += __shfl_down(ud, o);
        }
        if (lane == 0) {
            gdot[(size_t)row * CAP + slot] = gd;
            udot[(size_t)row * CAP + slot] = ud;
        }
    }
}

// ---- FUSED final: per-row exact top-32 among band (desc exact key, asc idx),
// gu = silu*u, then down-gather: out[n,:] = sum_k gu_k * dTb[idx_k, :]
__global__ __launch_bounds__(256) void k_finaldown(
    const int* __restrict__ band, const int* __restrict__ bandcnt,
    const float* __restrict__ gdot, const float* __restrict__ udot,
    const unsigned short* __restrict__ dTb, float* __restrict__ out)
{
    __shared__ float ckey[CAP];
    __shared__ float cgu[CAP];
    __shared__ int   cidx[CAP];
    __shared__ int   js[LK];
    __shared__ float wgt[LK];
    const int row = blockIdx.x;
    const int tid = threadIdx.x;
    const int lane = tid & 63;
    const int cnt = bandcnt[row];
    if (tid < CAP) { ckey[tid] = -1.f; cgu[tid] = 0.f; cidx[tid] = 0x7fffffff; }
    __syncthreads();
    if (tid < cnt) {
        float gd = gdot[(size_t)row * CAP + tid];
        float g = gd / (1.f + expf(-gd));
        ckey[tid] = fabsf(g);
        cgu[tid]  = g * udot[(size_t)row * CAP + tid];
        cidx[tid] = band[row * CAP + tid];
    }
    __syncthreads();
    if (tid < 64) {
        float k1 = ckey[lane], k2 = ckey[lane + 64], k3 = ckey[lane + 128];
        int   i1 = cidx[lane], i2 = cidx[lane + 64], i3 = cidx[lane + 128];
        int   p1 = lane, p2 = lane + 64, p3 = lane + 128;
        for (int slot = 0; slot < LK; ++slot) {
            float bk = k1; int bi_ = i1, bp = p1;
            if (k2 > bk || (k2 == bk && i2 < bi_)) { bk = k2; bi_ = i2; bp = p2; }
            if (k3 > bk || (k3 == bk && i3 < bi_)) { bk = k3; bi_ = i3; bp = p3; }
            #pragma unroll
            for (int o = 1; o < 64; o <<= 1) {
                float ok = __shfl_xor(bk, o);
                int  oi = __shfl_xor(bi_, o);
                int  op = __shfl_xor(bp, o);
                if (ok > bk || (ok == bk && oi < bi_)) { bk = ok; bi_ = oi; bp = op; }
            }
            if (lane == 0) {
                js[slot]  = bi_ & (LI - 1);
                wgt[slot] = cgu[bp < CAP ? bp : 0];
            }
            if (p1 == bp) { k1 = -1.f; i1 = 0x7fffffff; }
            if (p2 == bp) { k2 = -1.f; i2 = 0x7fffffff; }
            if (p3 == bp) { k3 = -1.f; i3 = 0x7fffffff; }
        }
    }
    __syncthreads();

    // down-gather (bf16 rows)
    float a[8] = {0.f,0.f,0.f,0.f,0.f,0.f,0.f,0.f};
    #pragma unroll 4
    for (int k = 0; k < LK; ++k) {
        const ushort8 v = *(const ushort8*)(dTb + (size_t)js[k] * LD + tid * 8);
        float wv = wgt[k];
        #pragma unroll
        for (int e = 0; e < 8; ++e)
            a[e] = fmaf(wv, __uint_as_float(((unsigned)v[e]) << 16), a[e]);
    }
    float* o = out + (size_t)row * LD + tid * 8;
    f32x4 o0 = {a[0], a[1], a[2], a[3]};
    f32x4 o1 = {a[4], a[5], a[6], a[7]};
    *(f32x4*)o = o0;
    *(f32x4*)(o + 4) = o1;
}

extern "C" void kernel_launch(void* const* d_in, const int* in_sizes, int n_in,
                              void* d_out, int out_size, void* d_ws, size_t ws_size,
                              hipStream_t stream)
{
    const float* x      = (const float*)d_in[0];
    const float* gate   = (const float*)d_in[1];
    const float* up     = (const float*)d_in[2];
    const float* down   = (const float*)d_in[3];
    const int* layer_idx = (const int*)d_in[4];
    float* out = (float*)d_out;

    // ---- ws layout
    const size_t NC_ = (size_t)LN * CAP;
    char* p = (char*)d_ws;
    int*   band    = (int*)p;            p += NC_ * 4;
    int*   bandcnt = (int*)p;            p += (size_t)LN * 4;
    int*   ghist   = (int*)p;            p += (size_t)LI * 4;
    int*   inv     = (int*)p;            p += (size_t)LI * DEPTH * 4;   // 3 MB
    float* gdot    = (float*)p;          p += NC_ * 4;
    float* udot    = (float*)p;          p += NC_ * 4;
    p = (char*)(((size_t)p + 255) & ~(size_t)255);

    const size_t xcnt = (size_t)LN * LD;
    const size_t wcnt = (size_t)LI * LD;
    unsigned short* xh = (unsigned short*)p;          // fp16
    unsigned short* wh = xh + xcnt;                   // fp16
    unsigned short* zk = wh + wcnt;                   // fp16 keys
    unsigned short* dTb = zk + (size_t)LN * LI;       // bf16
    char* big_end = (char*)(dTb + (size_t)LI * LD);

    if ((size_t)(big_end - (char*)d_ws) > ws_size) return;   // ws too small

    k_cvt2<<<2561, 256, 0, stream>>>(x, gate, layer_idx, xh, wh, ghist);
    k_gemm<<<1024, 256, 0, stream>>>(xh, wh, zk);
    k_select<<<LN, 256, 0, stream>>>(zk, band, bandcnt, ghist, inv);
    k_pairT<<<LI + 4096, 256, 0, stream>>>(x, gate, up, down, layer_idx,
                                           ghist, inv, gdot, udot, dTb);
    k_finaldown<<<LN, 256, 0, stream>>>(band, bandcnt, gdot, udot, dTb, out);
}

// Round 16
// 291.847 us; speedup vs baseline: 1.0038x; 1.0038x over previous
//
#include <hip/hip_runtime.h>
#include <hip/hip_fp16.h>
#include <math.h>

constexpr int LI = 8192;   // I (intermediate)
constexpr int LD = 2048;   // D (hidden)
constexpr int LN = 2048;   // N (tokens)
constexpr int LK = 32;     // top_k
constexpr int CAP = 192;   // candidate band cap per row
constexpr int DEPTH = 96;  // per-neuron inverted-list bucket depth

typedef short short8 __attribute__((ext_vector_type(8)));
typedef unsigned short ushort8 __attribute__((ext_vector_type(8)));
typedef _Float16 half8 __attribute__((ext_vector_type(8)));
typedef float f32x4 __attribute__((ext_vector_type(4)));
typedef const __attribute__((address_space(1))) void* gas1_t;
typedef __attribute__((address_space(3))) void* las3_t;

__device__ __forceinline__ void gload16(const void* g, void* l) {
    __builtin_amdgcn_global_load_lds((gas1_t)g, (las3_t)l, 16, 0, 0);
}
__device__ __forceinline__ unsigned short f2bf_rne(float f) {
    unsigned u = __float_as_uint(f);
    return (unsigned short)((u + 0x7fffu + ((u >> 16) & 1u)) >> 16);
}
__device__ __forceinline__ unsigned short f2h_rne(float f) {   // fp16 RNE bits
    return __half_as_ushort(__float2half(f));
}
__device__ __forceinline__ float h2f(unsigned short u) {
    return __half2float(__ushort_as_half(u));
}

// ---- fused fp32->fp16 convert: blocks [0,512) = x, [512,2560) = gate[l],
//      block 2560 zeroes ghist. 8 floats/thread, 16B ushort8 stores.
__global__ __launch_bounds__(256) void k_cvt2(
    const float* __restrict__ x, const float* __restrict__ gate,
    const int* __restrict__ layer_idx,
    unsigned short* __restrict__ xh, unsigned short* __restrict__ wh,
    int* __restrict__ ghist)
{
    if (blockIdx.x >= 2560) {          // ghist zero (replaces hipMemsetAsync)
        int t = threadIdx.x;
        #pragma unroll
        for (int b = 0; b < 32; ++b) ghist[t * 32 + b] = 0;
        return;
    }
    const float* src; unsigned short* dst; int n8, bid, nb;
    if (blockIdx.x < 512) {
        src = x; dst = xh; n8 = (LN * LD) / 8; bid = blockIdx.x; nb = 512;
    } else {
        src = gate + (size_t)layer_idx[0] * LI * LD; dst = wh;
        n8 = (LI * LD) / 8; bid = blockIdx.x - 512; nb = 2048;
    }
    int i = bid * 256 + threadIdx.x;
    int stride = nb * 256;
    for (; i < n8; i += stride) {
        f32x4 v0 = *(const f32x4*)(src + 8 * (size_t)i);
        f32x4 v1 = *(const f32x4*)(src + 8 * (size_t)i + 4);
        ushort8 h;
        h[0] = f2h_rne(v0[0]); h[1] = f2h_rne(v0[1]);
        h[2] = f2h_rne(v0[2]); h[3] = f2h_rne(v0[3]);
        h[4] = f2h_rne(v1[0]); h[5] = f2h_rne(v1[1]);
        h[6] = f2h_rne(v1[2]); h[7] = f2h_rne(v1[3]);
        ((ushort8*)dst)[i] = h;
    }
}

// ---- zk = fp16(|silu(x @ gw^T)|) via fp16 MFMA, 128x128 tile, BK=64.
// Standalone again (transpose un-fused). Structure verified rounds 4-14.
__global__ __launch_bounds__(256) void k_gemm(
    const unsigned short* __restrict__ xh, const unsigned short* __restrict__ wh,
    unsigned short* __restrict__ zk)
{
    __shared__ short lds[16384];   // Ah|Bh, each [128][64] fp16 = 16KB
    short* Ah = lds;
    short* Bh = lds + 8192;

    const int tid = threadIdx.x;
    const int w = tid >> 6, lane = tid & 63;
    const int flat = blockIdx.x;                     // 0..1023
    const int swz  = (flat & 7) * 128 + (flat >> 3); // bijective XCD swizzle
    const int bn = (swz >> 6) * 128;   // token rows
    const int bi = (swz & 63) * 128;   // neuron rows

    const int srow   = w * 32 + (lane >> 3);
    const int schunk = (lane & 7) ^ ((lane >> 3) & 7);
    const unsigned short* xbh = xh + (size_t)(bn + srow) * LD + schunk * 8;
    const unsigned short* wbh = wh + (size_t)(bi + srow) * LD + schunk * 8;

    f32x4 acc[4][4];
    #pragma unroll
    for (int m = 0; m < 4; ++m)
        #pragma unroll
        for (int n = 0; n < 4; ++n) acc[m][n] = (f32x4){0.f, 0.f, 0.f, 0.f};

    const int wm = (w >> 1) * 64, wn = (w & 1) * 64;

    #define STAGE(k0)                                                          \
        {                                                                      \
            _Pragma("unroll")                                                  \
            for (int t = 0; t < 4; ++t) {                                      \
                int ldo = (w * 32 + t * 8) * 64;                               \
                size_t go = (size_t)t * 8 * LD + (k0);                         \
                gload16(xbh + go, Ah + ldo);                                   \
                gload16(wbh + go, Bh + ldo);                                   \
            }                                                                  \
        }

    STAGE(0);
    __syncthreads();
    for (int k0 = 0;;) {
        #pragma unroll
        for (int ks = 0; ks < 2; ++ks) {
            half8 a_h[4], b_h[4];
            #pragma unroll
            for (int m = 0; m < 4; ++m) {
                int lr = wm + m * 16 + (lane & 15);
                int lc = ks * 4 + (lane >> 4);
                a_h[m] = *(const half8*)(Ah + lr * 64 + ((lc ^ (lr & 7)) << 3));
            }
            #pragma unroll
            for (int n = 0; n < 4; ++n) {
                int lr = wn + n * 16 + (lane & 15);
                int lc = ks * 4 + (lane >> 4);
                b_h[n] = *(const half8*)(Bh + lr * 64 + ((lc ^ (lr & 7)) << 3));
            }
            #pragma unroll
            for (int m = 0; m < 4; ++m)
                #pragma unroll
                for (int n = 0; n < 4; ++n)
                    acc[m][n] = __builtin_amdgcn_mfma_f32_16x16x32_f16(a_h[m], b_h[n], acc[m][n], 0, 0, 0);
        }
        k0 += 64;
        if (k0 >= LD) break;
        __syncthreads();
        STAGE(k0);
        __syncthreads();
    }

    // epilogue: key = fp16(|silu(z)|)
    #pragma unroll
    for (int m = 0; m < 4; ++m) {
        int rb = bn + wm + m * 16 + (lane >> 4) * 4;
        #pragma unroll
        for (int n = 0; n < 4; ++n) {
            int cb = bi + wn + n * 16 + (lane & 15);
            #pragma unroll
            for (int r = 0; r < 4; ++r) {
                float zv = acc[m][n][r];
                float g = zv / (1.f + expf(-zv));
                zk[(size_t)(rb + r) * LI + cb] = f2h_rne(fabsf(g));
            }
        }
    }
    #undef STAGE
}

// ---- band selection on fp16 keys: 2048 bins of 4-ulp width over [0.25, 64),
// threshold bin covering rank-32, band = keys >= binfloor - 0.012.
__global__ __launch_bounds__(256) void k_select(
    const unsigned short* __restrict__ zk, int* __restrict__ band,
    int* __restrict__ bandcnt, int* __restrict__ ghist, int* __restrict__ inv)
{
    __shared__ int hist[2048];   // 8 KB
    __shared__ int sums[256];
    __shared__ int base_s;
    __shared__ int thrbin_s;

    const int row = blockIdx.x;
    const int tid = threadIdx.x;
    const int lane = tid & 63;
    const unsigned short* __restrict__ z = zk + (size_t)row * LI;

    if (tid == 0) { thrbin_s = 0; base_s = 0; }
    for (int i = tid; i < 2048; i += 256) hist[i] = 0;
    __syncthreads();

    ushort8 kv[4];
    #pragma unroll
    for (int c = 0; c < 4; ++c) {
        kv[c] = *(const ushort8*)(z + c * 2048 + tid * 8);
        #pragma unroll
        for (int j = 0; j < 8; ++j) {
            int b = (int)(kv[c][j] >> 2) - 3328;   // fp16 0.25 = 0x3400
            if (b > 0) {
                b = b > 2047 ? 2047 : b;
                atomicAdd(&hist[b], 1);
            }
        }
    }
    __syncthreads();

    int own = 0;
    #pragma unroll
    for (int b = 0; b < 8; ++b) own += hist[tid * 8 + b];
    sums[tid] = own;
    __syncthreads();
    for (int st = 1; st < 256; st <<= 1) {   // suffix inclusive scan
        int v = (tid + st < 256) ? sums[tid + st] : 0;
        __syncthreads();
        sums[tid] += v;
        __syncthreads();
    }
    int after = (tid < 255) ? sums[tid + 1] : 0;
    if (after < LK && after + own >= LK) {   // unique crossing thread
        int cum = after;
        for (int b = 7; b >= 0; --b) {
            cum += hist[tid * 8 + b];
            if (cum >= LK) { thrbin_s = tid * 8 + b; break; }
        }
    }
    __syncthreads();
    const float bandlo =
        h2f((unsigned short)((thrbin_s + 3328) << 2)) - 0.012f;

    #pragma unroll
    for (int c = 0; c < 4; ++c) {
        unsigned flags = 0;
        #pragma unroll
        for (int j = 0; j < 8; ++j) {
            if (h2f(kv[c][j]) >= bandlo) flags |= (1u << j);
        }
        int cnt = __popc(flags);
        int pre = cnt;                        // wave inclusive scan
        #pragma unroll
        for (int o = 1; o < 64; o <<= 1) {
            int v = __shfl_up(pre, o);
            if (lane >= o) pre += v;
        }
        int wtotal = __shfl(pre, 63);
        int excl = pre - cnt;
        int wbase = 0;
        if (lane == 63 && wtotal) wbase = atomicAdd(&base_s, wtotal);
        wbase = __shfl(wbase, 63);
        int pos = wbase + excl;
        while (flags) {
            int j = __ffs(flags) - 1;
            flags &= flags - 1;
            if (pos < CAP) {
                int gi = c * 2048 + tid * 8 + j;
                band[row * CAP + pos] = gi;
                int p = atomicAdd(&ghist[gi], 1);
                if (p < DEPTH) inv[gi * DEPTH + p] = (row << 8) | pos;
            }
            ++pos;
        }
    }
    __syncthreads();
    if (tid == 0) bandcnt[row] = base_s < CAP ? base_s : CAP;
}

// ---- FUSED: blocks [0,LI) = neuron-major exact rescore (pure gather,
// latency-bound); blocks [LI, LI+4096) = transpose down -> dT bf16 (pure BW).
// Transpose hides under pair's idle bandwidth (round-10/12-verified pairing).
__global__ __launch_bounds__(256) void k_pairT(
    const float* __restrict__ x, const float* __restrict__ gate,
    const float* __restrict__ up, const float* __restrict__ down,
    const int* __restrict__ layer_idx,
    const int* __restrict__ ghist, const int* __restrict__ inv,
    float* __restrict__ gdot, float* __restrict__ udot,
    unsigned short* __restrict__ dTb)
{
    __shared__ float smem[4160];   // pair: gs|us (16 KB); transpose: 64x65 tile
    const int tid = threadIdx.x;

    if (blockIdx.x >= LI) {
        // ---------------- transpose body: 64x64 tiles (verified r8-14) ------
        float (*t)[65] = (float(*)[65])smem;
        const float* __restrict__ dw = down + (size_t)layer_idx[0] * LD * LI;
        const int bid2 = blockIdx.x - LI;
        const int bi = (bid2 & 127) * 64;   // I
        const int bd = (bid2 >> 7) * 64;    // D
        const int tx = tid & 63, ty = tid >> 6;   // ty in [0,4)
        #pragma unroll
        for (int it = 0; it < 16; ++it) {
            int r = ty + it * 4;
            t[r][tx] = dw[(size_t)(bd + r) * LI + bi + tx];
        }
        __syncthreads();
        #pragma unroll
        for (int it = 0; it < 16; ++it) {
            int rr = ty + it * 4;
            dTb[(size_t)(bi + rr) * LD + bd + tx] = f2bf_rne(t[tx][rr]);
        }
        return;
    }

    // ---------------- pair body (round-10/13 verified) ----------------
    float* gs = smem;
    float* us = smem + LD;
    const int j = blockIdx.x;
    const int lane = tid & 63, w = tid >> 6;
    int nj = ghist[j];
    if (nj == 0) return;
    if (nj > DEPTH) nj = DEPTH;
    const float* __restrict__ gr = gate + (size_t)layer_idx[0] * LI * LD + (size_t)j * LD;
    const float* __restrict__ ur = up   + (size_t)layer_idx[0] * LI * LD + (size_t)j * LD;
    for (int i = tid * 4; i < LD; i += 1024) {
        *(f32x4*)&gs[i] = *(const f32x4*)(gr + i);
        *(f32x4*)&us[i] = *(const f32x4*)(ur + i);
    }
    __syncthreads();
    const int base = j * DEPTH;
    for (int e = w; e < nj; e += 4) {
        int packed = inv[base + e];
        int row = packed >> 8, slot = packed & 255;
        const float* __restrict__ xr = x + (size_t)row * LD;
        float gd0 = 0.f, gd1 = 0.f, ud0 = 0.f, ud1 = 0.f;
        #pragma unroll
        for (int it = 0; it < 8; it += 2) {
            int i0 = lane * 4 + it * 256;
            int i1 = i0 + 256;
            f32x4 xa = *(const f32x4*)(xr + i0);
            f32x4 xb = *(const f32x4*)(xr + i1);
            gd0 = fmaf(xa[0], gs[i0+0], gd0); gd0 = fmaf(xa[1], gs[i0+1], gd0);
            gd0 = fmaf(xa[2], gs[i0+2], gd0); gd0 = fmaf(xa[3], gs[i0+3], gd0);
            ud0 = fmaf(xa[0], us[i0+0], ud0); ud0 = fmaf(xa[1], us[i0+1], ud0);
            ud0 = fmaf(xa[2], us[i0+2], ud0); ud0 = fmaf(xa[3], us[i0+3], ud0);
            gd1 = fmaf(xb[0], gs[i1+0], gd1); gd1 = fmaf(xb[1], gs[i1+1], gd1);
            gd1 = fmaf(xb[2], gs[i1+2], gd1); gd1 = fmaf(xb[3], gs[i1+3], gd1);
            ud1 = fmaf(xb[0], us[i1+0], ud1); ud1 = fmaf(xb[1], us[i1+1], ud1);
            ud1 = fmaf(xb[2], us[i1+2], ud1); ud1 = fmaf(xb[3], us[i1+3], ud1);
        }
        float gd = gd0 + gd1, ud = ud0 + ud1;
        #pragma unroll
        for (int o = 32; o; o >>= 1) {
            gd += __shfl_down(gd, o);
            ud += __shfl_down(ud, o);
        }
        if (lane == 0) {
            gdot[(size_t)row * CAP + slot] = gd;
            udot[(size_t)row * CAP + slot] = ud;
        }
    }
}

// ---- FUSED final: per-row exact top-32 among band (desc exact key, asc idx),
// gu = silu*u, then down-gather: out[n,:] = sum_k gu_k * dTb[idx_k, :]
__global__ __launch_bounds__(256) void k_finaldown(
    const int* __restrict__ band, const int* __restrict__ bandcnt,
    const float* __restrict__ gdot, const float* __restrict__ udot,
    const unsigned short* __restrict__ dTb, float* __restrict__ out)
{
    __shared__ float ckey[CAP];
    __shared__ float cgu[CAP];
    __shared__ int   cidx[CAP];
    __shared__ int   js[LK];
    __shared__ float wgt[LK];
    const int row = blockIdx.x;
    const int tid = threadIdx.x;
    const int lane = tid & 63;
    const int cnt = bandcnt[row];
    if (tid < CAP) { ckey[tid] = -1.f; cgu[tid] = 0.f; cidx[tid] = 0x7fffffff; }
    __syncthreads();
    if (tid < cnt) {
        float gd = gdot[(size_t)row * CAP + tid];
        float g = gd / (1.f + expf(-gd));
        ckey[tid] = fabsf(g);
        cgu[tid]  = g * udot[(size_t)row * CAP + tid];
        cidx[tid] = band[row * CAP + tid];
    }
    __syncthreads();
    if (tid < 64) {
        float k1 = ckey[lane], k2 = ckey[lane + 64], k3 = ckey[lane + 128];
        int   i1 = cidx[lane], i2 = cidx[lane + 64], i3 = cidx[lane + 128];
        int   p1 = lane, p2 = lane + 64, p3 = lane + 128;
        for (int slot = 0; slot < LK; ++slot) {
            float bk = k1; int bi_ = i1, bp = p1;
            if (k2 > bk || (k2 == bk && i2 < bi_)) { bk = k2; bi_ = i2; bp = p2; }
            if (k3 > bk || (k3 == bk && i3 < bi_)) { bk = k3; bi_ = i3; bp = p3; }
            #pragma unroll
            for (int o = 1; o < 64; o <<= 1) {
                float ok = __shfl_xor(bk, o);
                int  oi = __shfl_xor(bi_, o);
                int  op = __shfl_xor(bp, o);
                if (ok > bk || (ok == bk && oi < bi_)) { bk = ok; bi_ = oi; bp = op; }
            }
            if (lane == 0) {
                js[slot]  = bi_ & (LI - 1);
                wgt[slot] = cgu[bp < CAP ? bp : 0];
            }
            if (p1 == bp) { k1 = -1.f; i1 = 0x7fffffff; }
            if (p2 == bp) { k2 = -1.f; i2 = 0x7fffffff; }
            if (p3 == bp) { k3 = -1.f; i3 = 0x7fffffff; }
        }
    }
    __syncthreads();

    // down-gather (bf16 rows)
    float a[8] = {0.f,0.f,0.f,0.f,0.f,0.f,0.f,0.f};
    #pragma unroll 4
    for (int k = 0; k < LK; ++k) {
        const ushort8 v = *(const ushort8*)(dTb + (size_t)js[k] * LD + tid * 8);
        float wv = wgt[k];
        #pragma unroll
        for (int e = 0; e < 8; ++e)
            a[e] = fmaf(wv, __uint_as_float(((unsigned)v[e]) << 16), a[e]);
    }
    float* o = out + (size_t)row * LD + tid * 8;
    f32x4 o0 = {a[0], a[1], a[2], a[3]};
    f32x4 o1 = {a[4], a[5], a[6], a[7]};
    *(f32x4*)o = o0;
    *(f32x4*)(o + 4) = o1;
}

extern "C" void kernel_launch(void* const* d_in, const int* in_sizes, int n_in,
                              void* d_out, int out_size, void* d_ws, size_t ws_size,
                              hipStream_t stream)
{
    const float* x      = (const float*)d_in[0];
    const float* gate   = (const float*)d_in[1];
    const float* up     = (const float*)d_in[2];
    const float* down   = (const float*)d_in[3];
    const int* layer_idx = (const int*)d_in[4];
    float* out = (float*)d_out;

    // ---- ws layout
    const size_t NC_ = (size_t)LN * CAP;
    char* p = (char*)d_ws;
    int*   band    = (int*)p;            p += NC_ * 4;
    int*   bandcnt = (int*)p;            p += (size_t)LN * 4;
    int*   ghist   = (int*)p;            p += (size_t)LI * 4;
    int*   inv     = (int*)p;            p += (size_t)LI * DEPTH * 4;   // 3 MB
    float* gdot    = (float*)p;          p += NC_ * 4;
    float* udot    = (float*)p;          p += NC_ * 4;
    p = (char*)(((size_t)p + 255) & ~(size_t)255);

    const size_t xcnt = (size_t)LN * LD;
    const size_t wcnt = (size_t)LI * LD;
    unsigned short* xh = (unsigned short*)p;          // fp16
    unsigned short* wh = xh + xcnt;                   // fp16
    unsigned short* zk = wh + wcnt;                   // fp16 keys
    unsigned short* dTb = zk + (size_t)LN * LI;       // bf16
    char* big_end = (char*)(dTb + (size_t)LI * LD);

    if ((size_t)(big_end - (char*)d_ws) > ws_size) return;   // ws too small

    k_cvt2<<<2561, 256, 0, stream>>>(x, gate, layer_idx, xh, wh, ghist);
    k_gemm<<<1024, 256, 0, stream>>>(xh, wh, zk);
    k_select<<<LN, 256, 0, stream>>>(zk, band, bandcnt, ghist, inv);
    k_pairT<<<LI + 4096, 256, 0, stream>>>(x, gate, up, down, layer_idx,
                                           ghist, inv, gdot, udot, dTb);
    k_finaldown<<<LN, 256, 0, stream>>>(band, bandcnt, gdot, udot, dTb, out);
}

// Round 17
// 270.539 us; speedup vs baseline: 1.0829x; 1.0788x over previous
//
#include <hip/hip_runtime.h>
#include <hip/hip_fp16.h>
#include <math.h>

constexpr int LI = 8192;   // I (intermediate)
constexpr int LD = 2048;   // D (hidden)
constexpr int LN = 2048;   // N (tokens)
constexpr int LK = 32;     // top_k
constexpr int CAP = 192;   // candidate band cap per row
constexpr int DEPTH = 96;  // per-neuron inverted-list bucket depth

typedef short short8 __attribute__((ext_vector_type(8)));
typedef unsigned short ushort8 __attribute__((ext_vector_type(8)));
typedef _Float16 half8 __attribute__((ext_vector_type(8)));
typedef float f32x4 __attribute__((ext_vector_type(4)));
typedef const __attribute__((address_space(1))) void* gas1_t;
typedef __attribute__((address_space(3))) void* las3_t;

__device__ __forceinline__ void gload16(const void* g, void* l) {
    __builtin_amdgcn_global_load_lds((gas1_t)g, (las3_t)l, 16, 0, 0);
}
__device__ __forceinline__ unsigned short f2bf_rne(float f) {
    unsigned u = __float_as_uint(f);
    return (unsigned short)((u + 0x7fffu + ((u >> 16) & 1u)) >> 16);
}
__device__ __forceinline__ unsigned short f2h_rne(float f) {   // fp16 RNE bits
    return __half_as_ushort(__float2half(f));
}
__device__ __forceinline__ float h2f(unsigned short u) {
    return __half2float(__ushort_as_half(u));
}

// ---- fused fp32->fp16 convert: blocks [0,512) = x, [512,2560) = gate[l],
//      block 2560 zeroes ghist. 8 floats/thread, 16B ushort8 stores.
__global__ __launch_bounds__(256) void k_cvt2(
    const float* __restrict__ x, const float* __restrict__ gate,
    const int* __restrict__ layer_idx,
    unsigned short* __restrict__ xh, unsigned short* __restrict__ wh,
    int* __restrict__ ghist)
{
    if (blockIdx.x >= 2560) {          // ghist zero (replaces hipMemsetAsync)
        int t = threadIdx.x;
        #pragma unroll
        for (int b = 0; b < 32; ++b) ghist[t * 32 + b] = 0;
        return;
    }
    const float* src; unsigned short* dst; int n8, bid, nb;
    if (blockIdx.x < 512) {
        src = x; dst = xh; n8 = (LN * LD) / 8; bid = blockIdx.x; nb = 512;
    } else {
        src = gate + (size_t)layer_idx[0] * LI * LD; dst = wh;
        n8 = (LI * LD) / 8; bid = blockIdx.x - 512; nb = 2048;
    }
    int i = bid * 256 + threadIdx.x;
    int stride = nb * 256;
    for (; i < n8; i += stride) {
        f32x4 v0 = *(const f32x4*)(src + 8 * (size_t)i);
        f32x4 v1 = *(const f32x4*)(src + 8 * (size_t)i + 4);
        ushort8 h;
        h[0] = f2h_rne(v0[0]); h[1] = f2h_rne(v0[1]);
        h[2] = f2h_rne(v0[2]); h[3] = f2h_rne(v0[3]);
        h[4] = f2h_rne(v1[0]); h[5] = f2h_rne(v1[1]);
        h[6] = f2h_rne(v1[2]); h[7] = f2h_rne(v1[3]);
        ((ushort8*)dst)[i] = h;
    }
}

// ---- FUSED: blocks [0,1024) = zk GEMM (fp16 MFMA; structure verified r4-16);
//             blocks [1024, 5120) = transpose down[D,I] -> dT bf16 [I,D].
// NEW SWIZZLE: each XCD owns 8 bi-panels (w-set = 4MB = L2, stays resident
// across the bn sweep) x all 16 bn-panels (x streams). Ideal fetch ~96MB
// vs old 250MB (old swizzle streamed ALL 64 w-panels through every XCD).
__global__ __launch_bounds__(256) void k_gemmT(
    const unsigned short* __restrict__ xh, const unsigned short* __restrict__ wh,
    const float* __restrict__ down, const int* __restrict__ layer_idx,
    unsigned short* __restrict__ zk, unsigned short* __restrict__ dTb)
{
    __shared__ char smem[32768];
    const int tid = threadIdx.x;

    if (blockIdx.x >= 1024) {
        // ---------------- transpose body: 64x64 tiles (round-8 verified) ----
        float (*t)[65] = (float(*)[65])smem;
        const float* __restrict__ dw = down + (size_t)layer_idx[0] * LD * LI;
        const int bid2 = blockIdx.x - 1024;
        const int bi = (bid2 & 127) * 64;   // I
        const int bd = (bid2 >> 7) * 64;    // D
        const int tx = tid & 63, ty = tid >> 6;
        #pragma unroll
        for (int it = 0; it < 16; ++it) {
            int r = ty + it * 4;
            t[r][tx] = dw[(size_t)(bd + r) * LI + bi + tx];
        }
        __syncthreads();
        #pragma unroll
        for (int it = 0; it < 16; ++it) {
            int rr = ty + it * 4;
            dTb[(size_t)(bi + rr) * LD + bd + tx] = f2bf_rne(t[tx][rr]);
        }
        return;
    }

    // ---------------- GEMM body (fp16 inputs, fp32 accum) ----------------
    short* Ah = (short*)smem;           // [128][64] fp16 = 16KB
    short* Bh = (short*)smem + 8192;    // [128][64] fp16 = 16KB

    const int w = tid >> 6, lane = tid & 63;
    // XCD-aware swizzle v2: xcd = flat&7 (round-robin dispatch), l = flat>>3.
    // bi-panel = xcd*8 + (l&7)  -> 8 w-panels per XCD (4MB, L2-resident)
    // bn-panel = l>>3           -> all 16 x-panels per XCD (streamed)
    const int flat = blockIdx.x;                     // 0..1023
    const int xcd  = flat & 7;
    const int l    = flat >> 3;                      // 0..127
    const int bi = (xcd * 8 + (l & 7)) * 128;        // neuron rows
    const int bn = (l >> 3) * 128;                   // token rows

    const int srow   = w * 32 + (lane >> 3);
    const int schunk = (lane & 7) ^ ((lane >> 3) & 7);
    const unsigned short* xbh = xh + (size_t)(bn + srow) * LD + schunk * 8;
    const unsigned short* wbh = wh + (size_t)(bi + srow) * LD + schunk * 8;

    f32x4 acc[4][4];
    #pragma unroll
    for (int m = 0; m < 4; ++m)
        #pragma unroll
        for (int n = 0; n < 4; ++n) acc[m][n] = (f32x4){0.f, 0.f, 0.f, 0.f};

    const int wm = (w >> 1) * 64, wn = (w & 1) * 64;

    #define STAGE(k0)                                                          \
        {                                                                      \
            _Pragma("unroll")                                                  \
            for (int t = 0; t < 4; ++t) {                                      \
                int ldo = (w * 32 + t * 8) * 64;                               \
                size_t go = (size_t)t * 8 * LD + (k0);                         \
                gload16(xbh + go, Ah + ldo);                                   \
                gload16(wbh + go, Bh + ldo);                                   \
            }                                                                  \
        }

    STAGE(0);
    __syncthreads();
    for (int k0 = 0;;) {
        #pragma unroll
        for (int ks = 0; ks < 2; ++ks) {
            half8 a_h[4], b_h[4];
            #pragma unroll
            for (int m = 0; m < 4; ++m) {
                int lr = wm + m * 16 + (lane & 15);
                int lc = ks * 4 + (lane >> 4);
                a_h[m] = *(const half8*)(Ah + lr * 64 + ((lc ^ (lr & 7)) << 3));
            }
            #pragma unroll
            for (int n = 0; n < 4; ++n) {
                int lr = wn + n * 16 + (lane & 15);
                int lc = ks * 4 + (lane >> 4);
                b_h[n] = *(const half8*)(Bh + lr * 64 + ((lc ^ (lr & 7)) << 3));
            }
            #pragma unroll
            for (int m = 0; m < 4; ++m)
                #pragma unroll
                for (int n = 0; n < 4; ++n)
                    acc[m][n] = __builtin_amdgcn_mfma_f32_16x16x32_f16(a_h[m], b_h[n], acc[m][n], 0, 0, 0);
        }
        k0 += 64;
        if (k0 >= LD) break;
        __syncthreads();
        STAGE(k0);
        __syncthreads();
    }

    // epilogue: key = fp16(|silu(z)|)
    #pragma unroll
    for (int m = 0; m < 4; ++m) {
        int rb = bn + wm + m * 16 + (lane >> 4) * 4;
        #pragma unroll
        for (int n = 0; n < 4; ++n) {
            int cb = bi + wn + n * 16 + (lane & 15);
            #pragma unroll
            for (int r = 0; r < 4; ++r) {
                float zv = acc[m][n][r];
                float g = zv / (1.f + expf(-zv));
                zk[(size_t)(rb + r) * LI + cb] = f2h_rne(fabsf(g));
            }
        }
    }
    #undef STAGE
}

// ---- band selection on fp16 keys: 2048 bins of 4-ulp width over [0.25, 64),
// threshold bin covering rank-32, band = keys >= binfloor - 0.012.
__global__ __launch_bounds__(256) void k_select(
    const unsigned short* __restrict__ zk, int* __restrict__ band,
    int* __restrict__ bandcnt, int* __restrict__ ghist, int* __restrict__ inv)
{
    __shared__ int hist[2048];   // 8 KB
    __shared__ int sums[256];
    __shared__ int base_s;
    __shared__ int thrbin_s;

    const int row = blockIdx.x;
    const int tid = threadIdx.x;
    const int lane = tid & 63;
    const unsigned short* __restrict__ z = zk + (size_t)row * LI;

    if (tid == 0) { thrbin_s = 0; base_s = 0; }
    for (int i = tid; i < 2048; i += 256) hist[i] = 0;
    __syncthreads();

    ushort8 kv[4];
    #pragma unroll
    for (int c = 0; c < 4; ++c) {
        kv[c] = *(const ushort8*)(z + c * 2048 + tid * 8);
        #pragma unroll
        for (int j = 0; j < 8; ++j) {
            int b = (int)(kv[c][j] >> 2) - 3328;   // fp16 0.25 = 0x3400
            if (b > 0) {
                b = b > 2047 ? 2047 : b;
                atomicAdd(&hist[b], 1);
            }
        }
    }
    __syncthreads();

    int own = 0;
    #pragma unroll
    for (int b = 0; b < 8; ++b) own += hist[tid * 8 + b];
    sums[tid] = own;
    __syncthreads();
    for (int st = 1; st < 256; st <<= 1) {   // suffix inclusive scan
        int v = (tid + st < 256) ? sums[tid + st] : 0;
        __syncthreads();
        sums[tid] += v;
        __syncthreads();
    }
    int after = (tid < 255) ? sums[tid + 1] : 0;
    if (after < LK && after + own >= LK) {   // unique crossing thread
        int cum = after;
        for (int b = 7; b >= 0; --b) {
            cum += hist[tid * 8 + b];
            if (cum >= LK) { thrbin_s = tid * 8 + b; break; }
        }
    }
    __syncthreads();
    const float bandlo =
        h2f((unsigned short)((thrbin_s + 3328) << 2)) - 0.012f;

    #pragma unroll
    for (int c = 0; c < 4; ++c) {
        unsigned flags = 0;
        #pragma unroll
        for (int j = 0; j < 8; ++j) {
            if (h2f(kv[c][j]) >= bandlo) flags |= (1u << j);
        }
        int cnt = __popc(flags);
        int pre = cnt;                        // wave inclusive scan
        #pragma unroll
        for (int o = 1; o < 64; o <<= 1) {
            int v = __shfl_up(pre, o);
            if (lane >= o) pre += v;
        }
        int wtotal = __shfl(pre, 63);
        int excl = pre - cnt;
        int wbase = 0;
        if (lane == 63 && wtotal) wbase = atomicAdd(&base_s, wtotal);
        wbase = __shfl(wbase, 63);
        int pos = wbase + excl;
        while (flags) {
            int j = __ffs(flags) - 1;
            flags &= flags - 1;
            if (pos < CAP) {
                int gi = c * 2048 + tid * 8 + j;
                band[row * CAP + pos] = gi;
                int p = atomicAdd(&ghist[gi], 1);
                if (p < DEPTH) inv[gi * DEPTH + p] = (row << 8) | pos;
            }
            ++pos;
        }
    }
    __syncthreads();
    if (tid == 0) bandcnt[row] = base_s < CAP ? base_s : CAP;
}

// ---- neuron-major exact rescore (round-10/13/14 verified body, pure pair)
__global__ __launch_bounds__(256) void k_pair(
    const float* __restrict__ x, const float* __restrict__ gate,
    const float* __restrict__ up, const int* __restrict__ layer_idx,
    const int* __restrict__ ghist, const int* __restrict__ inv,
    float* __restrict__ gdot, float* __restrict__ udot)
{
    __shared__ float gs[LD];   // 8 KB
    __shared__ float us[LD];   // 8 KB
    const int j = blockIdx.x;
    const int tid = threadIdx.x;
    const int lane = tid & 63, w = tid >> 6;
    int nj = ghist[j];
    if (nj == 0) return;
    if (nj > DEPTH) nj = DEPTH;
    const float* __restrict__ gr = gate + (size_t)layer_idx[0] * LI * LD + (size_t)j * LD;
    const float* __restrict__ ur = up   + (size_t)layer_idx[0] * LI * LD + (size_t)j * LD;
    for (int i = tid * 4; i < LD; i += 1024) {
        *(f32x4*)&gs[i] = *(const f32x4*)(gr + i);
        *(f32x4*)&us[i] = *(const f32x4*)(ur + i);
    }
    __syncthreads();
    const int base = j * DEPTH;
    for (int e = w; e < nj; e += 4) {
        int packed = inv[base + e];
        int row = packed >> 8, slot = packed & 255;
        const float* __restrict__ xr = x + (size_t)row * LD;
        float gd0 = 0.f, gd1 = 0.f, ud0 = 0.f, ud1 = 0.f;
        #pragma unroll
        for (int it = 0; it < 8; it += 2) {
            int i0 = lane * 4 + it * 256;
            int i1 = i0 + 256;
            f32x4 xa = *(const f32x4*)(xr + i0);
            f32x4 xb = *(const f32x4*)(xr + i1);
            gd0 = fmaf(xa[0], gs[i0+0], gd0); gd0 = fmaf(xa[1], gs[i0+1], gd0);
            gd0 = fmaf(xa[2], gs[i0+2], gd0); gd0 = fmaf(xa[3], gs[i0+3], gd0);
            ud0 = fmaf(xa[0], us[i0+0], ud0); ud0 = fmaf(xa[1], us[i0+1], ud0);
            ud0 = fmaf(xa[2], us[i0+2], ud0); ud0 = fmaf(xa[3], us[i0+3], ud0);
            gd1 = fmaf(xb[0], gs[i1+0], gd1); gd1 = fmaf(xb[1], gs[i1+1], gd1);
            gd1 = fmaf(xb[2], gs[i1+2], gd1); gd1 = fmaf(xb[3], gs[i1+3], gd1);
            ud1 = fmaf(xb[0], us[i1+0], ud1); ud1 = fmaf(xb[1], us[i1+1], ud1);
            ud1 = fmaf(xb[2], us[i1+2], ud1); ud1 = fmaf(xb[3], us[i1+3], ud1);
        }
        float gd = gd0 + gd1, ud = ud0 + ud1;
        #pragma unroll
        for (int o = 32; o; o >>= 1) {
            gd += __shfl_down(gd, o);
            ud += __shfl_down(ud, o);
        }
        if (lane == 0) {
            gdot[(size_t)row * CAP + slot] = gd;
            udot[(size_t)row * CAP + slot] = ud;
        }
    }
}

// ---- FUSED final: per-row exact top-32 among band (desc exact key, asc idx),
// gu = silu*u, then down-gather: out[n,:] = sum_k gu_k * dTb[idx_k, :]
__global__ __launch_bounds__(256) void k_finaldown(
    const int* __restrict__ band, const int* __restrict__ bandcnt,
    const float* __restrict__ gdot, const float* __restrict__ udot,
    const unsigned short* __restrict__ dTb, float* __restrict__ out)
{
    __shared__ float ckey[CAP];
    __shared__ float cgu[CAP];
    __shared__ int   cidx[CAP];
    __shared__ int   js[LK];
    __shared__ float wgt[LK];
    const int row = blockIdx.x;
    const int tid = threadIdx.x;
    const int lane = tid & 63;
    const int cnt = bandcnt[row];
    if (tid < CAP) { ckey[tid] = -1.f; cgu[tid] = 0.f; cidx[tid] = 0x7fffffff; }
    __syncthreads();
    if (tid < cnt) {
        float gd = gdot[(size_t)row * CAP + tid];
        float g = gd / (1.f + expf(-gd));
        ckey[tid] = fabsf(g);
        cgu[tid]  = g * udot[(size_t)row * CAP + tid];
        cidx[tid] = band[row * CAP + tid];
    }
    __syncthreads();
    if (tid < 64) {
        float k1 = ckey[lane], k2 = ckey[lane + 64], k3 = ckey[lane + 128];
        int   i1 = cidx[lane], i2 = cidx[lane + 64], i3 = cidx[lane + 128];
        int   p1 = lane, p2 = lane + 64, p3 = lane + 128;
        for (int slot = 0; slot < LK; ++slot) {
            float bk = k1; int bi_ = i1, bp = p1;
            if (k2 > bk || (k2 == bk && i2 < bi_)) { bk = k2; bi_ = i2; bp = p2; }
            if (k3 > bk || (k3 == bk && i3 < bi_)) { bk = k3; bi_ = i3; bp = p3; }
            #pragma unroll
            for (int o = 1; o < 64; o <<= 1) {
                float ok = __shfl_xor(bk, o);
                int  oi = __shfl_xor(bi_, o);
                int  op = __shfl_xor(bp, o);
                if (ok > bk || (ok == bk && oi < bi_)) { bk = ok; bi_ = oi; bp = op; }
            }
            if (lane == 0) {
                js[slot]  = bi_ & (LI - 1);
                wgt[slot] = cgu[bp < CAP ? bp : 0];
            }
            if (p1 == bp) { k1 = -1.f; i1 = 0x7fffffff; }
            if (p2 == bp) { k2 = -1.f; i2 = 0x7fffffff; }
            if (p3 == bp) { k3 = -1.f; i3 = 0x7fffffff; }
        }
    }
    __syncthreads();

    // down-gather (bf16 rows)
    float a[8] = {0.f,0.f,0.f,0.f,0.f,0.f,0.f,0.f};
    #pragma unroll 4
    for (int k = 0; k < LK; ++k) {
        const ushort8 v = *(const ushort8*)(dTb + (size_t)js[k] * LD + tid * 8);
        float wv = wgt[k];
        #pragma unroll
        for (int e = 0; e < 8; ++e)
            a[e] = fmaf(wv, __uint_as_float(((unsigned)v[e]) << 16), a[e]);
    }
    float* o = out + (size_t)row * LD + tid * 8;
    f32x4 o0 = {a[0], a[1], a[2], a[3]};
    f32x4 o1 = {a[4], a[5], a[6], a[7]};
    *(f32x4*)o = o0;
    *(f32x4*)(o + 4) = o1;
}

extern "C" void kernel_launch(void* const* d_in, const int* in_sizes, int n_in,
                              void* d_out, int out_size, void* d_ws, size_t ws_size,
                              hipStream_t stream)
{
    const float* x      = (const float*)d_in[0];
    const float* gate   = (const float*)d_in[1];
    const float* up     = (const float*)d_in[2];
    const float* down   = (const float*)d_in[3];
    const int* layer_idx = (const int*)d_in[4];
    float* out = (float*)d_out;

    // ---- ws layout
    const size_t NC_ = (size_t)LN * CAP;
    char* p = (char*)d_ws;
    int*   band    = (int*)p;            p += NC_ * 4;
    int*   bandcnt = (int*)p;            p += (size_t)LN * 4;
    int*   ghist   = (int*)p;            p += (size_t)LI * 4;
    int*   inv     = (int*)p;            p += (size_t)LI * DEPTH * 4;   // 3 MB
    float* gdot    = (float*)p;          p += NC_ * 4;
    float* udot    = (float*)p;          p += NC_ * 4;
    p = (char*)(((size_t)p + 255) & ~(size_t)255);

    const size_t xcnt = (size_t)LN * LD;
    const size_t wcnt = (size_t)LI * LD;
    unsigned short* xh = (unsigned short*)p;          // fp16
    unsigned short* wh = xh + xcnt;                   // fp16
    unsigned short* zk = wh + wcnt;                   // fp16 keys
    unsigned short* dTb = zk + (size_t)LN * LI;       // bf16
    char* big_end = (char*)(dTb + (size_t)LI * LD);

    if ((size_t)(big_end - (char*)d_ws) > ws_size) return;   // ws too small

    k_cvt2<<<2561, 256, 0, stream>>>(x, gate, layer_idx, xh, wh, ghist);
    k_gemmT<<<5120, 256, 0, stream>>>(xh, wh, down, layer_idx, zk, dTb);
    k_select<<<LN, 256, 0, stream>>>(zk, band, bandcnt, ghist, inv);
    k_pair<<<LI, 256, 0, stream>>>(x, gate, up, layer_idx, ghist, inv, gdot, udot);
    k_finaldown<<<LN, 256, 0, stream>>>(band, bandcnt, gdot, udot, dTb, out);
}

// Round 18
// 244.941 us; speedup vs baseline: 1.1960x; 1.1045x over previous
//
#include <hip/hip_runtime.h>
#include <hip/hip_fp16.h>
#include <math.h>

constexpr int LI = 8192;   // I (intermediate)
constexpr int LD = 2048;   // D (hidden)
constexpr int LN = 2048;   // N (tokens)
constexpr int LK = 32;     // top_k
constexpr int CAP = 192;   // candidate band cap per row
constexpr int DEPTH = 96;  // per-neuron inverted-list bucket depth

typedef short short8 __attribute__((ext_vector_type(8)));
typedef unsigned short ushort8 __attribute__((ext_vector_type(8)));
typedef _Float16 half8 __attribute__((ext_vector_type(8)));
typedef float f32x4 __attribute__((ext_vector_type(4)));
typedef const __attribute__((address_space(1))) void* gas1_t;
typedef __attribute__((address_space(3))) void* las3_t;

__device__ __forceinline__ void gload16(const void* g, void* l) {
    __builtin_amdgcn_global_load_lds((gas1_t)g, (las3_t)l, 16, 0, 0);
}
__device__ __forceinline__ unsigned short f2bf_rne(float f) {
    unsigned u = __float_as_uint(f);
    return (unsigned short)((u + 0x7fffu + ((u >> 16) & 1u)) >> 16);
}
__device__ __forceinline__ unsigned short f2h_rne(float f) {   // fp16 RNE bits
    return __half_as_ushort(__float2half(f));
}
__device__ __forceinline__ float h2f(unsigned short u) {
    return __half2float(__ushort_as_half(u));
}

// ---- fused fp32->fp16 convert: blocks [0,512) = x, [512,2560) = gate[l],
//      block 2560 zeroes ghist+gbnd.
__global__ __launch_bounds__(256) void k_cvt2(
    const float* __restrict__ x, const float* __restrict__ gate,
    const int* __restrict__ layer_idx,
    unsigned short* __restrict__ xh, unsigned short* __restrict__ wh,
    int* __restrict__ ghist, int* __restrict__ gbnd)
{
    if (blockIdx.x >= 2560) {          // counters zero (replaces hipMemsetAsync)
        int t = threadIdx.x;
        #pragma unroll
        for (int b = 0; b < 32; ++b) {
            ghist[t * 32 + b] = 0;
            gbnd[t * 32 + b]  = 0;
        }
        return;
    }
    const float* src; unsigned short* dst; int n8, bid, nb;
    if (blockIdx.x < 512) {
        src = x; dst = xh; n8 = (LN * LD) / 8; bid = blockIdx.x; nb = 512;
    } else {
        src = gate + (size_t)layer_idx[0] * LI * LD; dst = wh;
        n8 = (LI * LD) / 8; bid = blockIdx.x - 512; nb = 2048;
    }
    int i = bid * 256 + threadIdx.x;
    int stride = nb * 256;
    for (; i < n8; i += stride) {
        f32x4 v0 = *(const f32x4*)(src + 8 * (size_t)i);
        f32x4 v1 = *(const f32x4*)(src + 8 * (size_t)i + 4);
        ushort8 h;
        h[0] = f2h_rne(v0[0]); h[1] = f2h_rne(v0[1]);
        h[2] = f2h_rne(v0[2]); h[3] = f2h_rne(v0[3]);
        h[4] = f2h_rne(v1[0]); h[5] = f2h_rne(v1[1]);
        h[6] = f2h_rne(v1[2]); h[7] = f2h_rne(v1[3]);
        ((ushort8*)dst)[i] = h;
    }
}

// ---- FUSED: blocks [0,1024) = zk GEMM (fp16 MFMA; structure verified r4-17);
//             blocks [1024, 5120) = transpose down[D,I] -> dT bf16 [I,D].
// zk now stores SIGNED fp16 silu(z) (selection takes |.| downstream).
__global__ __launch_bounds__(256) void k_gemmT(
    const unsigned short* __restrict__ xh, const unsigned short* __restrict__ wh,
    const float* __restrict__ down, const int* __restrict__ layer_idx,
    unsigned short* __restrict__ zk, unsigned short* __restrict__ dTb)
{
    __shared__ char smem[32768];
    const int tid = threadIdx.x;

    if (blockIdx.x >= 1024) {
        // ---------------- transpose body: 64x64 tiles (round-8 verified) ----
        float (*t)[65] = (float(*)[65])smem;
        const float* __restrict__ dw = down + (size_t)layer_idx[0] * LD * LI;
        const int bid2 = blockIdx.x - 1024;
        const int bi = (bid2 & 127) * 64;   // I
        const int bd = (bid2 >> 7) * 64;    // D
        const int tx = tid & 63, ty = tid >> 6;
        #pragma unroll
        for (int it = 0; it < 16; ++it) {
            int r = ty + it * 4;
            t[r][tx] = dw[(size_t)(bd + r) * LI + bi + tx];
        }
        __syncthreads();
        #pragma unroll
        for (int it = 0; it < 16; ++it) {
            int rr = ty + it * 4;
            dTb[(size_t)(bi + rr) * LD + bd + tx] = f2bf_rne(t[tx][rr]);
        }
        return;
    }

    // ---------------- GEMM body (fp16 inputs, fp32 accum) ----------------
    short* Ah = (short*)smem;           // [128][64] fp16 = 16KB
    short* Bh = (short*)smem + 8192;    // [128][64] fp16 = 16KB

    const int w = tid >> 6, lane = tid & 63;
    // XCD-aware swizzle v2 (verified r17: FETCH 283->99MB)
    const int flat = blockIdx.x;                     // 0..1023
    const int xcd  = flat & 7;
    const int l    = flat >> 3;                      // 0..127
    const int bi = (xcd * 8 + (l & 7)) * 128;        // neuron rows
    const int bn = (l >> 3) * 128;                   // token rows

    const int srow   = w * 32 + (lane >> 3);
    const int schunk = (lane & 7) ^ ((lane >> 3) & 7);
    const unsigned short* xbh = xh + (size_t)(bn + srow) * LD + schunk * 8;
    const unsigned short* wbh = wh + (size_t)(bi + srow) * LD + schunk * 8;

    f32x4 acc[4][4];
    #pragma unroll
    for (int m = 0; m < 4; ++m)
        #pragma unroll
        for (int n = 0; n < 4; ++n) acc[m][n] = (f32x4){0.f, 0.f, 0.f, 0.f};

    const int wm = (w >> 1) * 64, wn = (w & 1) * 64;

    #define STAGE(k0)                                                          \
        {                                                                      \
            _Pragma("unroll")                                                  \
            for (int t = 0; t < 4; ++t) {                                      \
                int ldo = (w * 32 + t * 8) * 64;                               \
                size_t go = (size_t)t * 8 * LD + (k0);                         \
                gload16(xbh + go, Ah + ldo);                                   \
                gload16(wbh + go, Bh + ldo);                                   \
            }                                                                  \
        }

    STAGE(0);
    __syncthreads();
    for (int k0 = 0;;) {
        #pragma unroll
        for (int ks = 0; ks < 2; ++ks) {
            half8 a_h[4], b_h[4];
            #pragma unroll
            for (int m = 0; m < 4; ++m) {
                int lr = wm + m * 16 + (lane & 15);
                int lc = ks * 4 + (lane >> 4);
                a_h[m] = *(const half8*)(Ah + lr * 64 + ((lc ^ (lr & 7)) << 3));
            }
            #pragma unroll
            for (int n = 0; n < 4; ++n) {
                int lr = wn + n * 16 + (lane & 15);
                int lc = ks * 4 + (lane >> 4);
                b_h[n] = *(const half8*)(Bh + lr * 64 + ((lc ^ (lr & 7)) << 3));
            }
            #pragma unroll
            for (int m = 0; m < 4; ++m)
                #pragma unroll
                for (int n = 0; n < 4; ++n)
                    acc[m][n] = __builtin_amdgcn_mfma_f32_16x16x32_f16(a_h[m], b_h[n], acc[m][n], 0, 0, 0);
        }
        k0 += 64;
        if (k0 >= LD) break;
        __syncthreads();
        STAGE(k0);
        __syncthreads();
    }

    // epilogue: zk = fp16(silu(z)) SIGNED
    #pragma unroll
    for (int m = 0; m < 4; ++m) {
        int rb = bn + wm + m * 16 + (lane >> 4) * 4;
        #pragma unroll
        for (int n = 0; n < 4; ++n) {
            int cb = bi + wn + n * 16 + (lane & 15);
            #pragma unroll
            for (int r = 0; r < 4; ++r) {
                float zv = acc[m][n][r];
                float g = zv / (1.f + expf(-zv));
                zk[(size_t)(rb + r) * LI + cb] = f2h_rne(g);
            }
        }
    }
    #undef STAGE
}

// ---- band selection on |fp16 keys|: 2048 bins of 4-ulp width over [0.25,64),
// threshold bin covering rank-32. Two tiers:
//   sure-in:  key >= binceil + 0.024  (provably in exact top-32; no rescore)
//   boundary: bandlo <= key < thr_sure (needs exact fp32 rescore for ranking)
__global__ __launch_bounds__(256) void k_select(
    const unsigned short* __restrict__ zk, int* __restrict__ band,
    int* __restrict__ bandcnt, int* __restrict__ ghist,
    int* __restrict__ gbnd, int* __restrict__ inv)
{
    __shared__ int hist[2048];   // 8 KB
    __shared__ int sums[256];
    __shared__ int base_s;
    __shared__ int thrbin_s;

    const int row = blockIdx.x;
    const int tid = threadIdx.x;
    const int lane = tid & 63;
    const unsigned short* __restrict__ z = zk + (size_t)row * LI;

    if (tid == 0) { thrbin_s = 0; base_s = 0; }
    for (int i = tid; i < 2048; i += 256) hist[i] = 0;
    __syncthreads();

    ushort8 kv[4];
    #pragma unroll
    for (int c = 0; c < 4; ++c) {
        kv[c] = *(const ushort8*)(z + c * 2048 + tid * 8);
        #pragma unroll
        for (int j = 0; j < 8; ++j) {
            int ka = (int)(kv[c][j] & 0x7FFF);     // |silu| bits
            int b = (ka >> 2) - 3328;              // fp16 0.25 = 0x3400
            if (b > 0) {
                b = b > 2047 ? 2047 : b;
                atomicAdd(&hist[b], 1);
            }
        }
    }
    __syncthreads();

    int own = 0;
    #pragma unroll
    for (int b = 0; b < 8; ++b) own += hist[tid * 8 + b];
    sums[tid] = own;
    __syncthreads();
    for (int st = 1; st < 256; st <<= 1) {   // suffix inclusive scan
        int v = (tid + st < 256) ? sums[tid + st] : 0;
        __syncthreads();
        sums[tid] += v;
        __syncthreads();
    }
    int after = (tid < 255) ? sums[tid + 1] : 0;
    if (after < LK && after + own >= LK) {   // unique crossing thread
        int cum = after;
        for (int b = 7; b >= 0; --b) {
            cum += hist[tid * 8 + b];
            if (cum >= LK) { thrbin_s = tid * 8 + b; break; }
        }
    }
    __syncthreads();
    const float bandlo =
        h2f((unsigned short)((thrbin_s + 3328) << 2)) - 0.012f;
    const float thr_sure =
        h2f((unsigned short)((thrbin_s + 1 + 3328) << 2)) + 0.024f;

    #pragma unroll
    for (int c = 0; c < 4; ++c) {
        unsigned flags = 0, bflags = 0;
        #pragma unroll
        for (int j = 0; j < 8; ++j) {
            float kf = h2f((unsigned short)(kv[c][j] & 0x7FFF));
            if (kf >= bandlo) {
                flags |= (1u << j);
                if (kf < thr_sure) bflags |= (1u << j);
            }
        }
        int cnt = __popc(flags);
        int pre = cnt;                        // wave inclusive scan
        #pragma unroll
        for (int o = 1; o < 64; o <<= 1) {
            int v = __shfl_up(pre, o);
            if (lane >= o) pre += v;
        }
        int wtotal = __shfl(pre, 63);
        int excl = pre - cnt;
        int wbase = 0;
        if (lane == 63 && wtotal) wbase = atomicAdd(&base_s, wtotal);
        wbase = __shfl(wbase, 63);
        int pos = wbase + excl;
        while (flags) {
            int j = __ffs(flags) - 1;
            flags &= flags - 1;
            int bnd = (bflags >> j) & 1;
            if (pos < CAP) {
                int gi = c * 2048 + tid * 8 + j;
                band[row * CAP + pos] = gi | (bnd << 15);
                int p = atomicAdd(&ghist[gi], 1);
                if (p < DEPTH) inv[gi * DEPTH + p] = (row << 9) | (bnd << 8) | pos;
                if (bnd) atomicAdd(&gbnd[gi], 1);
            }
            ++pos;
        }
    }
    __syncthreads();
    if (tid == 0) bandcnt[row] = base_s < CAP ? base_s : CAP;
}

// ---- neuron-major rescore: boundary entries = exact fp32 g+u (verified path);
// sure-in entries = u-dot only from fp16 xh (values only; error ~4e-5 in out).
__global__ __launch_bounds__(256) void k_pair(
    const float* __restrict__ x, const unsigned short* __restrict__ xh,
    const float* __restrict__ gate, const float* __restrict__ up,
    const int* __restrict__ layer_idx,
    const int* __restrict__ ghist, const int* __restrict__ gbnd,
    const int* __restrict__ inv,
    float* __restrict__ gdot, float* __restrict__ udot)
{
    __shared__ float gs[LD];   // 8 KB
    __shared__ float us[LD];   // 8 KB
    const int j = blockIdx.x;
    const int tid = threadIdx.x;
    const int lane = tid & 63, w = tid >> 6;
    int nj = ghist[j];
    if (nj == 0) return;
    if (nj > DEPTH) nj = DEPTH;
    const int hasb = gbnd[j];
    const float* __restrict__ ur = up + (size_t)layer_idx[0] * LI * LD + (size_t)j * LD;
    for (int i = tid * 4; i < LD; i += 1024)
        *(f32x4*)&us[i] = *(const f32x4*)(ur + i);
    if (hasb) {
        const float* __restrict__ gr = gate + (size_t)layer_idx[0] * LI * LD + (size_t)j * LD;
        for (int i = tid * 4; i < LD; i += 1024)
            *(f32x4*)&gs[i] = *(const f32x4*)(gr + i);
    }
    __syncthreads();
    const int base = j * DEPTH;
    for (int e = w; e < nj; e += 4) {
        int packed = inv[base + e];
        int row = packed >> 9, bnd = (packed >> 8) & 1, slot = packed & 255;
        if (bnd) {
            // exact fp32 dual-dot (verified r10-17 path)
            const float* __restrict__ xr = x + (size_t)row * LD;
            float gd0 = 0.f, gd1 = 0.f, ud0 = 0.f, ud1 = 0.f;
            #pragma unroll
            for (int it = 0; it < 8; it += 2) {
                int i0 = lane * 4 + it * 256;
                int i1 = i0 + 256;
                f32x4 xa = *(const f32x4*)(xr + i0);
                f32x4 xb = *(const f32x4*)(xr + i1);
                gd0 = fmaf(xa[0], gs[i0+0], gd0); gd0 = fmaf(xa[1], gs[i0+1], gd0);
                gd0 = fmaf(xa[2], gs[i0+2], gd0); gd0 = fmaf(xa[3], gs[i0+3], gd0);
                ud0 = fmaf(xa[0], us[i0+0], ud0); ud0 = fmaf(xa[1], us[i0+1], ud0);
                ud0 = fmaf(xa[2], us[i0+2], ud0); ud0 = fmaf(xa[3], us[i0+3], ud0);
                gd1 = fmaf(xb[0], gs[i1+0], gd1); gd1 = fmaf(xb[1], gs[i1+1], gd1);
                gd1 = fmaf(xb[2], gs[i1+2], gd1); gd1 = fmaf(xb[3], gs[i1+3], gd1);
                ud1 = fmaf(xb[0], us[i1+0], ud1); ud1 = fmaf(xb[1], us[i1+1], ud1);
                ud1 = fmaf(xb[2], us[i1+2], ud1); ud1 = fmaf(xb[3], us[i1+3], ud1);
            }
            float gd = gd0 + gd1, ud = ud0 + ud1;
            #pragma unroll
            for (int o = 32; o; o >>= 1) {
                gd += __shfl_down(gd, o);
                ud += __shfl_down(ud, o);
            }
            if (lane == 0) {
                gdot[(size_t)row * CAP + slot] = gd;
                udot[(size_t)row * CAP + slot] = ud;
            }
        } else {
            // sure-in: u-dot from fp16 x row (half the gather bytes)
            const unsigned short* __restrict__ xrh = xh + (size_t)row * LD;
            float ud0 = 0.f, ud1 = 0.f;
            #pragma unroll
            for (int it = 0; it < 4; ++it) {
                int ib = lane * 8 + it * 512;
                ushort8 hv = *(const ushort8*)(xrh + ib);
                ud0 = fmaf(h2f(hv[0]), us[ib+0], ud0);
                ud0 = fmaf(h2f(hv[1]), us[ib+1], ud0);
                ud0 = fmaf(h2f(hv[2]), us[ib+2], ud0);
                ud0 = fmaf(h2f(hv[3]), us[ib+3], ud0);
                ud1 = fmaf(h2f(hv[4]), us[ib+4], ud1);
                ud1 = fmaf(h2f(hv[5]), us[ib+5], ud1);
                ud1 = fmaf(h2f(hv[6]), us[ib+6], ud1);
                ud1 = fmaf(h2f(hv[7]), us[ib+7], ud1);
            }
            float ud = ud0 + ud1;
            #pragma unroll
            for (int o = 32; o; o >>= 1) ud += __shfl_down(ud, o);
            if (lane == 0) udot[(size_t)row * CAP + slot] = ud;
        }
    }
}

// ---- FUSED final: sure-ins auto-selected (g from signed zk); boundary ranked
// by exact key (desc, idx asc); gu = g*u; down-gather from bf16 dTb.
__global__ __launch_bounds__(256) void k_finaldown(
    const int* __restrict__ band, const int* __restrict__ bandcnt,
    const float* __restrict__ gdot, const float* __restrict__ udot,
    const unsigned short* __restrict__ zk,
    const unsigned short* __restrict__ dTb, float* __restrict__ out)
{
    __shared__ float ckey[CAP];
    __shared__ float cgu[CAP];
    __shared__ int   cidx[CAP];
    __shared__ int   js[LK];
    __shared__ float wgt[LK];
    const int row = blockIdx.x;
    const int tid = threadIdx.x;
    const int lane = tid & 63;
    const int cnt = bandcnt[row];
    if (tid < CAP) { ckey[tid] = -1.f; cgu[tid] = 0.f; cidx[tid] = 0x7fffffff; }
    __syncthreads();
    if (tid < cnt) {
        int v = band[row * CAP + tid];
        int gi = v & (LI - 1);
        float g;
        if ((v >> 15) & 1) {                       // boundary: exact rescore
            float gd = gdot[(size_t)row * CAP + tid];
            g = gd / (1.f + expf(-gd));
            ckey[tid] = fabsf(g);
        } else {                                   // sure-in: value from zk
            g = h2f(zk[(size_t)row * LI + gi]);
            ckey[tid] = 1e30f;                     // guaranteed selection
        }
        cgu[tid]  = g * udot[(size_t)row * CAP + tid];
        cidx[tid] = gi;
    }
    __syncthreads();
    if (tid < 64) {
        float k1 = ckey[lane], k2 = ckey[lane + 64], k3 = ckey[lane + 128];
        int   i1 = cidx[lane], i2 = cidx[lane + 64], i3 = cidx[lane + 128];
        int   p1 = lane, p2 = lane + 64, p3 = lane + 128;
        for (int slot = 0; slot < LK; ++slot) {
            float bk = k1; int bi_ = i1, bp = p1;
            if (k2 > bk || (k2 == bk && i2 < bi_)) { bk = k2; bi_ = i2; bp = p2; }
            if (k3 > bk || (k3 == bk && i3 < bi_)) { bk = k3; bi_ = i3; bp = p3; }
            #pragma unroll
            for (int o = 1; o < 64; o <<= 1) {
                float ok = __shfl_xor(bk, o);
                int  oi = __shfl_xor(bi_, o);
                int  op = __shfl_xor(bp, o);
                if (ok > bk || (ok == bk && oi < bi_)) { bk = ok; bi_ = oi; bp = op; }
            }
            if (lane == 0) {
                js[slot]  = bi_ & (LI - 1);
                wgt[slot] = cgu[bp < CAP ? bp : 0];
            }
            if (p1 == bp) { k1 = -1.f; i1 = 0x7fffffff; }
            if (p2 == bp) { k2 = -1.f; i2 = 0x7fffffff; }
            if (p3 == bp) { k3 = -1.f; i3 = 0x7fffffff; }
        }
    }
    __syncthreads();

    // down-gather (bf16 rows)
    float a[8] = {0.f,0.f,0.f,0.f,0.f,0.f,0.f,0.f};
    #pragma unroll 4
    for (int k = 0; k < LK; ++k) {
        const ushort8 v = *(const ushort8*)(dTb + (size_t)js[k] * LD + tid * 8);
        float wv = wgt[k];
        #pragma unroll
        for (int e = 0; e < 8; ++e)
            a[e] = fmaf(wv, __uint_as_float(((unsigned)v[e]) << 16), a[e]);
    }
    float* o = out + (size_t)row * LD + tid * 8;
    f32x4 o0 = {a[0], a[1], a[2], a[3]};
    f32x4 o1 = {a[4], a[5], a[6], a[7]};
    *(f32x4*)o = o0;
    *(f32x4*)(o + 4) = o1;
}

extern "C" void kernel_launch(void* const* d_in, const int* in_sizes, int n_in,
                              void* d_out, int out_size, void* d_ws, size_t ws_size,
                              hipStream_t stream)
{
    const float* x      = (const float*)d_in[0];
    const float* gate   = (const float*)d_in[1];
    const float* up     = (const float*)d_in[2];
    const float* down   = (const float*)d_in[3];
    const int* layer_idx = (const int*)d_in[4];
    float* out = (float*)d_out;

    // ---- ws layout
    const size_t NC_ = (size_t)LN * CAP;
    char* p = (char*)d_ws;
    int*   band    = (int*)p;            p += NC_ * 4;
    int*   bandcnt = (int*)p;            p += (size_t)LN * 4;
    int*   ghist   = (int*)p;            p += (size_t)LI * 4;
    int*   gbnd    = (int*)p;            p += (size_t)LI * 4;
    int*   inv     = (int*)p;            p += (size_t)LI * DEPTH * 4;   // 3 MB
    float* gdot    = (float*)p;          p += NC_ * 4;
    float* udot    = (float*)p;          p += NC_ * 4;
    p = (char*)(((size_t)p + 255) & ~(size_t)255);

    const size_t xcnt = (size_t)LN * LD;
    const size_t wcnt = (size_t)LI * LD;
    unsigned short* xh = (unsigned short*)p;          // fp16
    unsigned short* wh = xh + xcnt;                   // fp16
    unsigned short* zk = wh + wcnt;                   // fp16 signed silu
    unsigned short* dTb = zk + (size_t)LN * LI;       // bf16
    char* big_end = (char*)(dTb + (size_t)LI * LD);

    if ((size_t)(big_end - (char*)d_ws) > ws_size) return;   // ws too small

    k_cvt2<<<2561, 256, 0, stream>>>(x, gate, layer_idx, xh, wh, ghist, gbnd);
    k_gemmT<<<5120, 256, 0, stream>>>(xh, wh, down, layer_idx, zk, dTb);
    k_select<<<LN, 256, 0, stream>>>(zk, band, bandcnt, ghist, gbnd, inv);
    k_pair<<<LI, 256, 0, stream>>>(x, xh, gate, up, layer_idx, ghist, gbnd, inv,
                                   gdot, udot);
    k_finaldown<<<LN, 256, 0, stream>>>(band, bandcnt, gdot, udot, zk, dTb, out);
}